// Round 3
// baseline (4455.449 us; speedup 1.0000x reference)
//
#include <hip/hip_runtime.h>

// LSTM: B=65536, L=6, H=50, T=3, IN=3, FC 50->1.
// R3: force register-resident operands.
// - Block = 64 samples (lanes) x 8 waves. Each wave handles 7 gate-quads
//   starting at j0 = w*50/8 (ranges overlap by 6 total: duplicated j's compute
//   identical values from identical staged inputs -> duplicate LDS writes are
//   benign and deterministic). Uniform CNT=7 -> single fully-unrolled code path.
// - Two-pass gates: pass A (x-part) has xr[50]+z[7][4] live; pass B (h-part)
//   has hr[50]+z[7][4] live. Peak ~105 VGPR < 128 cap -> no remat/re-read.
// - c[7] in registers (static index) -> no cl LDS array; LDS = ys only (38.4KB).
// - ys[T][H][64] in LDS, overwritten in place layer by layer.
// - Weights/biases via wave-uniform s_loads (j0 readfirstlane'd, jj static).

namespace {

constexpr int H     = 50;
constexpr int L     = 6;
constexpr int T     = 3;
constexpr int IN    = 3;
constexpr int LANES = 64;
constexpr int S     = 8;
constexpr int BLK   = LANES * S;  // 512
constexpr int CNT   = 7;          // uniform j-quads per wave (overlapping split)

__device__ __forceinline__ float fast_exp(float x) {
  return __builtin_amdgcn_exp2f(x * 1.44269504088896340736f);
}
__device__ __forceinline__ float sigm(float x) {
  return __builtin_amdgcn_rcpf(1.0f + fast_exp(-x));
}
__device__ __forceinline__ float tanh_(float x) {
  return 1.0f - 2.0f * __builtin_amdgcn_rcpf(1.0f + fast_exp(2.0f * x));
}

// One full layer (T steps) for this block's 64 samples; this wave owns
// j in [j0, j0+CNT) (may overlap neighbor waves -> duplicate identical work).
template <int NIN>
__device__ __forceinline__ void layer_run(
    const float* __restrict__ Wih,  // [4H][NIN] row-major (uniform)
    const float* __restrict__ Whh,  // [4H][H]   row-major (uniform)
    const float* __restrict__ bi,   // [4H] (uniform)
    const float* __restrict__ bh,   // [4H] (uniform)
    const float* __restrict__ xg,   // layer0 only: &x[b*IN*T] (per-thread)
    const float* __restrict__ h0g,  // &h0[(l*B+b)*H] (per-thread)
    const float* __restrict__ c0g,  // &c0[(l*B+b)*H] (per-thread)
    float* __restrict__ ys,         // LDS [T][H][LANES]
    int lane, int j0) {
  float c[CNT];
#pragma unroll
  for (int jj = 0; jj < CNT; ++jj) c[jj] = c0g[j0 + jj];

#pragma unroll 1
  for (int t = 0; t < T; ++t) {
    // ---------- stage x_t ----------
    float xr[NIN];
    if constexpr (NIN == IN) {
#pragma unroll
      for (int i = 0; i < NIN; ++i) xr[i] = xg[i * T + t];  // x[b][i][t]
    } else {
#pragma unroll
      for (int k = 0; k < NIN; ++k) xr[k] = ys[(t * H + k) * LANES + lane];
    }
    __syncthreads();  // all ys[t] stage-reads done before pass-B overwrites it

    // ---------- pass A: z = b + Wih @ x_t ----------
    float z[CNT][4];
#pragma unroll
    for (int jj = 0; jj < CNT; ++jj) {
      const int j = j0 + jj;
      z[jj][0] = bi[j]         + bh[j];
      z[jj][1] = bi[j + H]     + bh[j + H];
      z[jj][2] = bi[j + 2 * H] + bh[j + 2 * H];
      z[jj][3] = bi[j + 3 * H] + bh[j + 3 * H];
      const float* wi = Wih + j * NIN;
#pragma unroll
      for (int k = 0; k < NIN; ++k) {
        const float xk = xr[k];
        z[jj][0] = fmaf(wi[k],               xk, z[jj][0]);
        z[jj][1] = fmaf(wi[k + H * NIN],     xk, z[jj][1]);
        z[jj][2] = fmaf(wi[k + 2 * H * NIN], xk, z[jj][2]);
        z[jj][3] = fmaf(wi[k + 3 * H * NIN], xk, z[jj][3]);
      }
    }

    // ---------- stage h_{t-1} (xr dead; hr reuses its registers) ----------
    float hr[H];
    if (t == 0) {
#pragma unroll
      for (int k = 0; k < H; ++k) hr[k] = h0g[k];
    } else {
#pragma unroll
      for (int k = 0; k < H; ++k) hr[k] = ys[((t - 1) * H + k) * LANES + lane];
    }

    // ---------- pass B: z += Whh @ h, activations, c/h update ----------
#pragma unroll
    for (int jj = 0; jj < CNT; ++jj) {
      const int j = j0 + jj;
      const float* wh = Whh + j * H;
#pragma unroll
      for (int k = 0; k < H; ++k) {
        const float hk = hr[k];
        z[jj][0] = fmaf(wh[k],             hk, z[jj][0]);
        z[jj][1] = fmaf(wh[k + H * H],     hk, z[jj][1]);
        z[jj][2] = fmaf(wh[k + 2 * H * H], hk, z[jj][2]);
        z[jj][3] = fmaf(wh[k + 3 * H * H], hk, z[jj][3]);
      }
      const float ig = sigm(z[jj][0]);
      const float fg = sigm(z[jj][1]);
      const float gg = tanh_(z[jj][2]);
      const float og = sigm(z[jj][3]);
      const float cv = fmaf(fg, c[jj], ig * gg);
      c[jj] = cv;
      ys[(t * H + j) * LANES + lane] = og * tanh_(cv);  // new h_t
    }
    __syncthreads();  // ys[t] writes visible before next step's stage-reads
  }
}

__global__ __launch_bounds__(BLK, 4)  // cap 128 VGPR -> 4 waves/SIMD, 16/CU
void lstm_all(const float* __restrict__ x,      // [B,IN,T]
              const float* __restrict__ h0,     // [L,B,H]
              const float* __restrict__ c0,     // [L,B,H]
              const float* __restrict__ w_ih0,  // [4H,IN]
              const float* __restrict__ w_ihL,  // [L-1,4H,H]
              const float* __restrict__ w_hh,   // [L,4H,H]
              const float* __restrict__ b_ih,   // [L,4H]
              const float* __restrict__ b_hh,   // [L,4H]
              const float* __restrict__ fc_w,   // [H]
              const float* __restrict__ fc_b,   // [1]
              float* __restrict__ out,          // [B]
              int B) {
  const int lane = threadIdx.x & (LANES - 1);
  const int w    = threadIdx.x >> 6;
  const int b    = blockIdx.x * LANES + lane;

  // wave-uniform j-range start (overlapping split: 8 waves x 7 covers 50)
  const int j0 = __builtin_amdgcn_readfirstlane((w * H) / S);

  __shared__ float ys[T * H * LANES];  // 38400 B

  // ---------------- layer 0 ----------------
  layer_run<IN>(w_ih0, w_hh, b_ih, b_hh,
                x + (size_t)b * IN * T,
                h0 + (size_t)b * H,
                c0 + (size_t)b * H,
                ys, lane, j0);

  // ---------------- layers 1..L-1 ----------------
#pragma unroll 1
  for (int l = 1; l < L; ++l) {
    layer_run<H>(w_ihL + (size_t)(l - 1) * 4 * H * H,
                 w_hh + (size_t)l * 4 * H * H,
                 b_ih + l * 4 * H,
                 b_hh + l * 4 * H,
                 nullptr,
                 h0 + ((size_t)l * B + b) * H,
                 c0 + ((size_t)l * B + b) * H,
                 ys, lane, j0);
  }

  // ---------------- fc on last timestep's h (ys[T-1]) ----------------
  if (w == 0) {
    float acc = fc_b[0];
#pragma unroll
    for (int k = 0; k < H; ++k)
      acc = fmaf(fc_w[k], ys[((T - 1) * H + k) * LANES + lane], acc);
    out[b] = acc;
  }
}

}  // namespace

extern "C" void kernel_launch(void* const* d_in, const int* in_sizes, int n_in,
                              void* d_out, int out_size, void* d_ws, size_t ws_size,
                              hipStream_t stream) {
  const float* x     = (const float*)d_in[0];
  const float* h0    = (const float*)d_in[1];
  const float* c0    = (const float*)d_in[2];
  const float* w_ih0 = (const float*)d_in[3];
  const float* w_ih  = (const float*)d_in[4];
  const float* w_hh  = (const float*)d_in[5];
  const float* b_ih  = (const float*)d_in[6];
  const float* b_hh  = (const float*)d_in[7];
  const float* fc_w  = (const float*)d_in[8];
  const float* fc_b  = (const float*)d_in[9];
  float* out         = (float*)d_out;

  const int B = in_sizes[0] / (IN * T);  // 65536

  lstm_all<<<B / LANES, BLK, 0, stream>>>(x, h0, c0, w_ih0, w_ih, w_hh,
                                          b_ih, b_hh, fc_w, fc_b, out, B);
}

// Round 4
// 559.265 us; speedup vs baseline: 7.9666x; 7.9666x over previous
//
#include <hip/hip_runtime.h>

// LSTM B=65536, L=6, H=50, T=3, IN=3, FC 50->1 — split-bf16 MFMA version.
//
// D = gates^T = W·X^T via v_mfma_f32_16x16x32_bf16 (A=W frag, B=X frag).
// Gate rows interleaved: n = 4j+gate (N=256 padded, j<64, j<50 real).
// C-layout row = 16nt + 4q + reg  ->  gate = reg, j = 4*nt_global + q:
// all 4 gates of unit j land in one lane's 4 acc regs -> lane-local c/h update.
// Split fp32 = bf16_hi + bf16_lo; z = Whi·Xhi + Whi·Xlo + Wlo·Xhi (~fp32 acc).
// K = 128: slabs 0-1 = x-part (k<64), slabs 2-3 = h-part; bias folded into
// W at h-part k=63 against constant X column 1.0.
// Block = 32 samples, 4 waves (wave ng owns n-tiles 4ng..4ng+3, both m-tiles).
// ys[t][m][k] bf16 hi/lo in LDS, overwritten in place layer by layer (R2 trick).
// Weights: prologue kernel packs per-(layer,slab,ntile,hi/lo) A-fragments into
// d_ws, lane-major 16B/lane -> coalesced dwordx4; cached in VGPRs per layer.

namespace {

constexpr int H  = 50;
constexpr int L  = 6;
constexpr int T  = 3;
constexpr int IN = 3;
constexpr int M  = 32;    // samples per block
constexpr int BLK = 256;  // 4 waves
constexpr int ROWS = 72;  // ys row stride in ushort (144 B: uniform bank spread, 16B-aligned)

using short8 = __attribute__((ext_vector_type(8))) short;
using f32x4  = __attribute__((ext_vector_type(4))) float;

__device__ __forceinline__ float fexp(float x) { return __builtin_amdgcn_exp2f(x * 1.44269504088896f); }
__device__ __forceinline__ float sigm(float x) { return __builtin_amdgcn_rcpf(1.f + fexp(-x)); }
__device__ __forceinline__ float tanh_(float x) { return 1.f - 2.f * __builtin_amdgcn_rcpf(1.f + fexp(2.f * x)); }

__device__ __forceinline__ unsigned short bf_hi(float v) {  // f32 -> bf16 RNE
  unsigned u = __float_as_uint(v);
  return (unsigned short)((u + 0x7fffu + ((u >> 16) & 1u)) >> 16);
}
__device__ __forceinline__ float bf_f(unsigned short h) { return __uint_as_float(((unsigned)h) << 16); }

// ---------------- prologue: pack weights into A-fragment layout ----------------
// frag id f = ((l*4 + s)*16 + nt)*2 + p ; element (f*64+lane)*8 + jj (bf16).
// Frag for lane: W[n = 16*nt + (lane&15)][k = 32*s + (lane>>4)*8 + jj].
__global__ void wprep(const float* __restrict__ w_ih0, const float* __restrict__ w_ihL,
                      const float* __restrict__ w_hh,  const float* __restrict__ b_ih,
                      const float* __restrict__ b_hh,  unsigned short* __restrict__ wbuf) {
  int t = blockIdx.x * 256 + threadIdx.x;
  if (t >= 768 * 64) return;
  int lam = t & 63, f = t >> 6;
  int p = f & 1, nt = (f >> 1) & 15, s = (f >> 5) & 3, l = f >> 7;
  int n = nt * 16 + (lam & 15);
  int j = n >> 2, gate = n & 3, row = gate * 50 + j;  // PyTorch gate order i,f,g,o
  unsigned short out8[8];
#pragma unroll
  for (int jj = 0; jj < 8; ++jj) {
    int k = s * 32 + (lam >> 4) * 8 + jj;
    float v = 0.f;
    if (j < H) {
      if (s < 2) {                       // x-part, k in [0,64)
        int ksz = (l == 0) ? IN : H;
        if (k < ksz) v = (l == 0) ? w_ih0[row * IN + k]
                                  : w_ihL[((size_t)(l - 1) * 200 + row) * H + k];
      } else {                           // h-part, kh in [0,64)
        int kh = k - 64;
        if (kh < H)        v = w_hh[((size_t)l * 200 + row) * H + kh];
        else if (kh == 63) v = b_ih[l * 200 + row] + b_hh[l * 200 + row];  // bias row
      }
    }
    unsigned short hi = bf_hi(v);
    out8[jj] = (p == 0) ? hi : bf_hi(v - bf_f(hi));
  }
  ((short8*)wbuf)[t] = *(short8*)out8;
}

// ---------------- main kernel ----------------
__global__ __launch_bounds__(BLK, 2)  // 2 waves/SIMD -> 256-VGPR cap (W cache = 128)
void lstm_mfma(const float* __restrict__ x,   const float* __restrict__ h0,
               const float* __restrict__ c0,  const float* __restrict__ fc_w,
               const float* __restrict__ fc_b, const unsigned short* __restrict__ wbuf,
               float* __restrict__ out, int B) {
  const int tid = threadIdx.x;
  const int lam = tid & 63;
  const int ng  = tid >> 6;      // wave id = n-group
  const int q   = lam >> 4;
  const int lm  = lam & 15;
  const int bbase = blockIdx.x * M;

  __shared__ __align__(16) unsigned short ys_hi[T][M][ROWS];
  __shared__ __align__(16) unsigned short ys_lo[T][M][ROWS];
  __shared__ __align__(16) unsigned short hb_hi[M][ROWS];
  __shared__ __align__(16) unsigned short hb_lo[M][ROWS];

  // ---- stage x into ys (layer-0 X), k>=IN zero, k==63 = 1.0 (bias col) ----
  for (int idx = tid; idx < T * M * 64; idx += BLK) {
    int t = idx >> 11;          // /(M*64)
    int r = idx & 2047;
    int m = r >> 6, k = r & 63;
    float v = (k < IN) ? x[(size_t)(bbase + m) * (IN * T) + k * T + t]
                       : (k == 63 ? 1.f : 0.f);
    unsigned short hi = bf_hi(v);
    ys_hi[t][m][k] = hi;
    ys_lo[t][m][k] = bf_hi(v - bf_f(hi));
  }
  __syncthreads();

  float  c[4][2];
  f32x4  acc[4][2];
  short8 W[4][4][2];            // [nt][slab][hi/lo] — 128 VGPRs, per-layer cache

  for (int l = 0; l < L; ++l) {
    // ---- stage c0 through hb (f32 split across the two ushort arrays) ----
    for (int idx = tid; idx < M * 64; idx += BLK) {
      int m = idx >> 6, k = idx & 63;
      float cv = (k < H) ? c0[((size_t)l * B + bbase + m) * H + k] : 0.f;
      unsigned u = __float_as_uint(cv);
      hb_hi[m][k] = (unsigned short)(u >> 16);
      hb_lo[m][k] = (unsigned short)(u & 0xffffu);
    }
    __syncthreads();
#pragma unroll
    for (int nt = 0; nt < 4; ++nt)
#pragma unroll
      for (int mt = 0; mt < 2; ++mt) {
        int j = 16 * ng + 4 * nt + q, m = mt * 16 + lm;
        c[nt][mt] = __uint_as_float(((unsigned)hb_hi[m][j] << 16) | hb_lo[m][j]);
      }
    __syncthreads();
    // ---- stage h0 (t=0 h-source) into hb, bf16 hi/lo, k==63 = 1.0 ----
    for (int idx = tid; idx < M * 64; idx += BLK) {
      int m = idx >> 6, k = idx & 63;
      float v = (k < H) ? h0[((size_t)l * B + bbase + m) * H + k]
                        : (k == 63 ? 1.f : 0.f);
      unsigned short hi = bf_hi(v);
      hb_hi[m][k] = hi;
      hb_lo[m][k] = bf_hi(v - bf_f(hi));
    }
    __syncthreads();
    // ---- load this wave's W fragments for the layer (coalesced dwordx4) ----
#pragma unroll
    for (int nt = 0; nt < 4; ++nt)
#pragma unroll
      for (int s = 0; s < 4; ++s)
#pragma unroll
        for (int p = 0; p < 2; ++p) {
          int f = ((l * 4 + s) * 16 + (ng * 4 + nt)) * 2 + p;
          W[nt][s][p] = ((const short8*)wbuf)[f * 64 + lam];
        }

    // ---- timesteps ----
    for (int t = 0; t < T; ++t) {
#pragma unroll
      for (int nt = 0; nt < 4; ++nt)
#pragma unroll
        for (int mt = 0; mt < 2; ++mt) acc[nt][mt] = (f32x4){0.f, 0.f, 0.f, 0.f};

#pragma unroll
      for (int s = 0; s < 4; ++s) {
        const unsigned short* sh;
        const unsigned short* sl;
        int koff;
        if (s < 2)       { sh = &ys_hi[t][0][0];      sl = &ys_lo[t][0][0];      koff = s * 32; }
        else if (t == 0) { sh = &hb_hi[0][0];         sl = &hb_lo[0][0];         koff = (s - 2) * 32; }
        else             { sh = &ys_hi[t - 1][0][0];  sl = &ys_lo[t - 1][0][0];  koff = (s - 2) * 32; }
        short8 Xh[2], Xl[2];
#pragma unroll
        for (int mt = 0; mt < 2; ++mt) {  // B-frag: col m = lane&15, k = q*8+jj (contig)
          int off = (mt * 16 + lm) * ROWS + koff + q * 8;
          Xh[mt] = *(const short8*)(sh + off);
          Xl[mt] = *(const short8*)(sl + off);
        }
#pragma unroll
        for (int nt = 0; nt < 4; ++nt)
#pragma unroll
          for (int mt = 0; mt < 2; ++mt) {
            acc[nt][mt] = __builtin_amdgcn_mfma_f32_16x16x32_bf16(W[nt][s][0], Xh[mt], acc[nt][mt], 0, 0, 0);
            acc[nt][mt] = __builtin_amdgcn_mfma_f32_16x16x32_bf16(W[nt][s][0], Xl[mt], acc[nt][mt], 0, 0, 0);
            acc[nt][mt] = __builtin_amdgcn_mfma_f32_16x16x32_bf16(W[nt][s][1], Xh[mt], acc[nt][mt], 0, 0, 0);
          }
      }
      __syncthreads();  // all X reads of ys[t]/ys[t-1]/hb done before in-place h-writes

      // ---- h-phase: acc regs 0..3 = gates i,f,g,o of unit j (lane-local) ----
#pragma unroll
      for (int nt = 0; nt < 4; ++nt)
#pragma unroll
        for (int mt = 0; mt < 2; ++mt) {
          float ig = sigm(acc[nt][mt][0]);
          float fg = sigm(acc[nt][mt][1]);
          float gg = tanh_(acc[nt][mt][2]);
          float og = sigm(acc[nt][mt][3]);
          float cv = fg * c[nt][mt] + ig * gg;
          c[nt][mt] = cv;
          float hv = og * tanh_(cv);
          int j = 16 * ng + 4 * nt + q;
          if (j < H) {                     // keep zero pad (and k63=1.0) intact
            int m = mt * 16 + lm;
            unsigned short hi = bf_hi(hv);
            ys_hi[t][m][j] = hi;
            ys_lo[t][m][j] = bf_hi(hv - bf_f(hi));
          }
        }
      __syncthreads();  // h_t visible before step t+1 reads
    }
  }

  // ---- fc tail: out[b] = fc_w · h_last + fc_b ----
  {
    int m = tid >> 3, strip = tid & 7;
    float part = 0.f;
#pragma unroll
    for (int jj = 0; jj < 8; ++jj) {
      int j = strip * 8 + jj;
      if (j < H)
        part += fc_w[j] * (bf_f(ys_hi[2][m][j]) + bf_f(ys_lo[2][m][j]));
    }
    part += __shfl_xor(part, 4);
    part += __shfl_xor(part, 2);
    part += __shfl_xor(part, 1);
    if (strip == 0) out[bbase + m] = part + fc_b[0];
  }
}

}  // namespace

extern "C" void kernel_launch(void* const* d_in, const int* in_sizes, int n_in,
                              void* d_out, int out_size, void* d_ws, size_t ws_size,
                              hipStream_t stream) {
  const float* x     = (const float*)d_in[0];
  const float* h0    = (const float*)d_in[1];
  const float* c0    = (const float*)d_in[2];
  const float* w_ih0 = (const float*)d_in[3];
  const float* w_ih  = (const float*)d_in[4];
  const float* w_hh  = (const float*)d_in[5];
  const float* b_ih  = (const float*)d_in[6];
  const float* b_hh  = (const float*)d_in[7];
  const float* fc_w  = (const float*)d_in[8];
  const float* fc_b  = (const float*)d_in[9];
  float* out         = (float*)d_out;

  const int B = in_sizes[0] / (IN * T);  // 65536
  unsigned short* wbuf = (unsigned short*)d_ws;  // 768 frags * 64 lanes * 16 B = 786 KB

  wprep<<<(768 * 64 + 255) / 256, 256, 0, stream>>>(w_ih0, w_ih, w_hh, b_ih, b_hh, wbuf);
  lstm_mfma<<<B / M, BLK, 0, stream>>>(x, h0, c0, fc_w, fc_b, wbuf, out, B);
}

// Round 5
// 401.036 us; speedup vs baseline: 11.1098x; 1.3945x over previous
//
#include <hip/hip_runtime.h>

// LSTM B=65536, L=6, H=50, T=3, IN=3, FC 50->1 — split-bf16 MFMA, R5.
//
// R5 changes vs R4 (448us, occupancy 23%: W-cache 128 VGPR + 32 AGPR acc ->
// ~250 unified regs -> 2 waves/SIMD):
//  - 8 waves/block (BLK=512), each wave owns 2 n-tiles -> W cache 64 regs.
//  - 2-term split: z = Whi*Xhi + Whi*Xlo (drop Wlo*Xhi; weight-residual noise
//    ~2e-4/gate -> ~1.5e-3 at output, threshold 6.25e-3). W cache -> 32 regs,
//    MFMA count -33%.
//  - n-tile-pair rotation by blockIdx so pad tiles (j>=52) spread over SIMDs.
//  - launch_bounds(512,3): no forced spill; actual ~110 regs -> HW grants 4/SIMD.
//
// Layout (unchanged): gates^T = W·X^T, n = 4j+gate, 16x16x32 bf16 MFMA;
// C row = 4q+reg -> lane holds all 4 gates of unit j = 4*tile+q (lane-local
// c/h update). X rows [m][k] stride 72 ushorts (b128 reads spread 8 lanes per
// bank-quad = BW floor). ys[t] overwritten in place across layers; bias folded
// at h-part k=63 vs constant 1.0 column.

namespace {

constexpr int H  = 50;
constexpr int L  = 6;
constexpr int T  = 3;
constexpr int IN = 3;
constexpr int M  = 32;     // samples per block
constexpr int BLK = 512;   // 8 waves
constexpr int ROWS = 72;   // ushort row stride (144 B)

using short8 = __attribute__((ext_vector_type(8))) short;
using f32x4  = __attribute__((ext_vector_type(4))) float;

__device__ __forceinline__ float fexp(float x) { return __builtin_amdgcn_exp2f(x * 1.44269504088896f); }
__device__ __forceinline__ float sigm(float x) { return __builtin_amdgcn_rcpf(1.f + fexp(-x)); }
__device__ __forceinline__ float tanh_(float x) { return 1.f - 2.f * __builtin_amdgcn_rcpf(1.f + fexp(2.f * x)); }

__device__ __forceinline__ unsigned short bf_hi(float v) {  // f32 -> bf16 RNE
  unsigned u = __float_as_uint(v);
  return (unsigned short)((u + 0x7fffu + ((u >> 16) & 1u)) >> 16);
}
__device__ __forceinline__ float bf_f(unsigned short h) { return __uint_as_float(((unsigned)h) << 16); }

// ---------------- prologue: pack weights into A-fragment layout ----------------
// frag id f = ((l*4 + s)*16 + nt)*2 + p ; element (f*64+lane)*8 + jj (bf16).
// Lane's frag: W[n = 16*nt + (lane&15)][k = 32*s + (lane>>4)*8 + jj].
__global__ void wprep(const float* __restrict__ w_ih0, const float* __restrict__ w_ihL,
                      const float* __restrict__ w_hh,  const float* __restrict__ b_ih,
                      const float* __restrict__ b_hh,  unsigned short* __restrict__ wbuf) {
  int t = blockIdx.x * 256 + threadIdx.x;
  if (t >= 768 * 64) return;
  int lam = t & 63, f = t >> 6;
  int p = f & 1, nt = (f >> 1) & 15, s = (f >> 5) & 3, l = f >> 7;
  int n = nt * 16 + (lam & 15);
  int j = n >> 2, gate = n & 3, row = gate * 50 + j;  // PyTorch gate order i,f,g,o
  unsigned short out8[8];
#pragma unroll
  for (int jj = 0; jj < 8; ++jj) {
    int k = s * 32 + (lam >> 4) * 8 + jj;
    float v = 0.f;
    if (j < H) {
      if (s < 2) {                       // x-part, k in [0,64)
        int ksz = (l == 0) ? IN : H;
        if (k < ksz) v = (l == 0) ? w_ih0[row * IN + k]
                                  : w_ihL[((size_t)(l - 1) * 200 + row) * H + k];
      } else {                           // h-part, kh in [0,64)
        int kh = k - 64;
        if (kh < H)        v = w_hh[((size_t)l * 200 + row) * H + kh];
        else if (kh == 63) v = b_ih[l * 200 + row] + b_hh[l * 200 + row];  // bias
      }
    }
    unsigned short hi = bf_hi(v);
    out8[jj] = (p == 0) ? hi : bf_hi(v - bf_f(hi));
  }
  ((short8*)wbuf)[t] = *(short8*)out8;
}

// ---------------- main kernel ----------------
__global__ __launch_bounds__(BLK, 3)
void lstm_mfma(const float* __restrict__ x,   const float* __restrict__ h0,
               const float* __restrict__ c0,  const float* __restrict__ fc_w,
               const float* __restrict__ fc_b, const unsigned short* __restrict__ wbuf,
               float* __restrict__ out, int B) {
  const int tid = threadIdx.x;
  const int lam = tid & 63;
  const int q   = lam >> 4;
  const int lm  = lam & 15;
  const int bbase = blockIdx.x * M;
  // wave's n-tile pair, rotated per block so pad tiles spread across SIMDs
  const int ng  = __builtin_amdgcn_readfirstlane(tid >> 6);
  const int ntp = __builtin_amdgcn_readfirstlane((ng + blockIdx.x) & 7);

  __shared__ __align__(16) unsigned short ys_hi[T][M][ROWS];
  __shared__ __align__(16) unsigned short ys_lo[T][M][ROWS];
  __shared__ __align__(16) unsigned short hb_hi[M][ROWS];
  __shared__ __align__(16) unsigned short hb_lo[M][ROWS];

  // ---- stage x into ys (layer-0 X): k<IN = x, k==63 = 1.0 (bias col), else 0
  for (int idx = tid; idx < T * M * 64; idx += BLK) {
    int t = idx >> 11;
    int r = idx & 2047;
    int m = r >> 6, k = r & 63;
    float v = (k < IN) ? x[(size_t)(bbase + m) * (IN * T) + k * T + t]
                       : (k == 63 ? 1.f : 0.f);
    unsigned short hi = bf_hi(v);
    ys_hi[t][m][k] = hi;
    ys_lo[t][m][k] = bf_hi(v - bf_f(hi));
  }
  __syncthreads();

  float  c[2][2];
  f32x4  acc[2][2];
  short8 W[2][4];   // [nt][kslab], hi-part only — 32 VGPRs

  for (int l = 0; l < L; ++l) {
    // ---- stage c0 through hb (f32 split across the two ushort arrays) ----
    for (int idx = tid; idx < M * 64; idx += BLK) {
      int m = idx >> 6, k = idx & 63;
      float cv = (k < H) ? c0[((size_t)l * B + bbase + m) * H + k] : 0.f;
      unsigned u = __float_as_uint(cv);
      hb_hi[m][k] = (unsigned short)(u >> 16);
      hb_lo[m][k] = (unsigned short)(u & 0xffffu);
    }
    __syncthreads();
#pragma unroll
    for (int nt = 0; nt < 2; ++nt)
#pragma unroll
      for (int mt = 0; mt < 2; ++mt) {
        int j = 4 * (2 * ntp + nt) + q, m = mt * 16 + lm;
        c[nt][mt] = (j < H)
            ? __uint_as_float(((unsigned)hb_hi[m][j] << 16) | hb_lo[m][j]) : 0.f;
      }
    __syncthreads();
    // ---- stage h0 (t=0 h-source) into hb, bf16 hi/lo, k==63 = 1.0 ----
    for (int idx = tid; idx < M * 64; idx += BLK) {
      int m = idx >> 6, k = idx & 63;
      float v = (k < H) ? h0[((size_t)l * B + bbase + m) * H + k]
                        : (k == 63 ? 1.f : 0.f);
      unsigned short hi = bf_hi(v);
      hb_hi[m][k] = hi;
      hb_lo[m][k] = bf_hi(v - bf_f(hi));
    }
    // ---- load this wave's W fragments for the layer (hi only, coalesced) ----
#pragma unroll
    for (int nt = 0; nt < 2; ++nt)
#pragma unroll
      for (int s = 0; s < 4; ++s) {
        int f = (((l * 4 + s) * 16 + (2 * ntp + nt)) * 2 + 0);
        W[nt][s] = ((const short8*)wbuf)[f * 64 + lam];
      }
    __syncthreads();  // hb ready before t=0 reads it

    // ---- timesteps ----
    for (int t = 0; t < T; ++t) {
#pragma unroll
      for (int nt = 0; nt < 2; ++nt)
#pragma unroll
        for (int mt = 0; mt < 2; ++mt) acc[nt][mt] = (f32x4){0.f, 0.f, 0.f, 0.f};

#pragma unroll
      for (int s = 0; s < 4; ++s) {
        const unsigned short* sh;
        const unsigned short* sl;
        int koff;
        if (s < 2)       { sh = &ys_hi[t][0][0];      sl = &ys_lo[t][0][0];      koff = s * 32; }
        else if (t == 0) { sh = &hb_hi[0][0];         sl = &hb_lo[0][0];         koff = (s - 2) * 32; }
        else             { sh = &ys_hi[t - 1][0][0];  sl = &ys_lo[t - 1][0][0];  koff = (s - 2) * 32; }
        short8 Xh[2], Xl[2];
#pragma unroll
        for (int mt = 0; mt < 2; ++mt) {  // B-frag: col m = lane&15, k = q*8+jj
          int off = (mt * 16 + lm) * ROWS + koff + q * 8;
          Xh[mt] = *(const short8*)(sh + off);
          Xl[mt] = *(const short8*)(sl + off);
        }
#pragma unroll
        for (int nt = 0; nt < 2; ++nt)
#pragma unroll
          for (int mt = 0; mt < 2; ++mt) {
            acc[nt][mt] = __builtin_amdgcn_mfma_f32_16x16x32_bf16(W[nt][s], Xh[mt], acc[nt][mt], 0, 0, 0);
            acc[nt][mt] = __builtin_amdgcn_mfma_f32_16x16x32_bf16(W[nt][s], Xl[mt], acc[nt][mt], 0, 0, 0);
          }
      }
      __syncthreads();  // X reads done before in-place h-writes

      // ---- h-phase: acc regs 0..3 = gates i,f,g,o of unit j (lane-local) ----
#pragma unroll
      for (int nt = 0; nt < 2; ++nt)
#pragma unroll
        for (int mt = 0; mt < 2; ++mt) {
          float ig = sigm(acc[nt][mt][0]);
          float fg = sigm(acc[nt][mt][1]);
          float gg = tanh_(acc[nt][mt][2]);
          float og = sigm(acc[nt][mt][3]);
          float cv = fg * c[nt][mt] + ig * gg;
          c[nt][mt] = cv;
          float hv = og * tanh_(cv);
          int j = 4 * (2 * ntp + nt) + q;
          if (j < H) {                     // keep zero pad and k63=1.0 intact
            int m = mt * 16 + lm;
            unsigned short hi = bf_hi(hv);
            ys_hi[t][m][j] = hi;
            ys_lo[t][m][j] = bf_hi(hv - bf_f(hi));
          }
        }
      __syncthreads();  // h_t visible before step t+1 reads
    }
  }

  // ---- fc tail: out[b] = fc_w · h_last + fc_b ----
  {
    int m = tid >> 4, strip = tid & 15;
    float part = 0.f;
#pragma unroll
    for (int jj = 0; jj < 4; ++jj) {
      int j = strip * 4 + jj;
      if (j < H)
        part += fc_w[j] * (bf_f(ys_hi[2][m][j]) + bf_f(ys_lo[2][m][j]));
    }
    part += __shfl_xor(part, 8);
    part += __shfl_xor(part, 4);
    part += __shfl_xor(part, 2);
    part += __shfl_xor(part, 1);
    if (strip == 0) out[bbase + m] = part + fc_b[0];
  }
}

}  // namespace

extern "C" void kernel_launch(void* const* d_in, const int* in_sizes, int n_in,
                              void* d_out, int out_size, void* d_ws, size_t ws_size,
                              hipStream_t stream) {
  const float* x     = (const float*)d_in[0];
  const float* h0    = (const float*)d_in[1];
  const float* c0    = (const float*)d_in[2];
  const float* w_ih0 = (const float*)d_in[3];
  const float* w_ih  = (const float*)d_in[4];
  const float* w_hh  = (const float*)d_in[5];
  const float* b_ih  = (const float*)d_in[6];
  const float* b_hh  = (const float*)d_in[7];
  const float* fc_w  = (const float*)d_in[8];
  const float* fc_b  = (const float*)d_in[9];
  float* out         = (float*)d_out;

  const int B = in_sizes[0] / (IN * T);  // 65536
  unsigned short* wbuf = (unsigned short*)d_ws;  // 768 frags * 64 lanes * 16 B

  wprep<<<(768 * 64 + 255) / 256, 256, 0, stream>>>(w_ih0, w_ih, w_hh, b_ih, b_hh, wbuf);
  lstm_mfma<<<B / M, BLK, 0, stream>>>(x, h0, c0, fc_w, fc_b, wbuf, out, B);
}

// Round 6
// 333.661 us; speedup vs baseline: 13.3532x; 1.2019x over previous
//
#include <hip/hip_runtime.h>

// LSTM B=65536, L=6, H=50, T=3, IN=3, FC 50->1 — single-term fp16 MFMA, R6.
//
// R6 vs R5 (282us kernel): fp16 replaces split-bf16 entirely. Single
// mfma_f32_16x16x32_f16 per (nt,mt,slab) — fp16's 11-bit mantissa gives
// z-noise ~2.4e-4, better than R5's 2-term bf16 (measured 2e-3). Halves MFMA
// count, LDS arrays, ds traffic, and cvt work.
//  - Layer ping-pong ys[2][T][M][ROWS]: step t reads ys[src][t] (x-part) and
//    ys[dst][hs] (h-part, hs = t==0 ? T-1 : t-1), writes ys[dst][t]. Nobody
//    reads ys[dst][t] during step t -> ONE barrier per step (after h-write).
//  - h0 staged coalesced into ys[dst][T-1] at layer start (slot is consumed at
//    t=0, rewritten only at t=T-1). Kills the hb arrays.
//  - c0 loaded straight to registers (lane-local scattered, L2-aggregated).
//  - Bias folded into W h-part k=63 vs constant 1.0 column (pad cols keep
//    k in [50,63) = 0, k==63 = 1.0 in both buffers, maintained by invariant:
//    h-writes only touch j < 50).
// Layout: gates^T = W·X^T, n = 4j+gate; C row = 4q+reg -> lane holds all 4
// gates of unit j = 4*tile+q (lane-local c/h update). Same verified mapping
// as R4/R5.

namespace {

constexpr int H  = 50;
constexpr int L  = 6;
constexpr int T  = 3;
constexpr int IN = 3;
constexpr int M  = 32;     // samples per block
constexpr int BLK = 512;   // 8 waves
constexpr int ROWS = 72;   // _Float16 row stride (144 B): b128 reads 2-way-free

using half8 = __attribute__((ext_vector_type(8))) _Float16;
using f32x4 = __attribute__((ext_vector_type(4))) float;

__device__ __forceinline__ float fexp(float x) { return __builtin_amdgcn_exp2f(x * 1.44269504088896f); }
__device__ __forceinline__ float sigm(float x) { return __builtin_amdgcn_rcpf(1.f + fexp(-x)); }
__device__ __forceinline__ float tanh_(float x) { return 1.f - 2.f * __builtin_amdgcn_rcpf(1.f + fexp(2.f * x)); }

// ---------------- prologue: pack fp16 A-fragments ----------------
// frag id f = (l*4 + s)*16 + nt ; lane's frag: W[n=16*nt+(lam&15)][k=32*s+(lam>>4)*8+jj]
__global__ void wprep(const float* __restrict__ w_ih0, const float* __restrict__ w_ihL,
                      const float* __restrict__ w_hh,  const float* __restrict__ b_ih,
                      const float* __restrict__ b_hh,  _Float16* __restrict__ wbuf) {
  int t = blockIdx.x * 256 + threadIdx.x;
  if (t >= 384 * 64) return;
  int lam = t & 63, f = t >> 6;
  int nt = f & 15, s = (f >> 4) & 3, l = f >> 6;
  int n = nt * 16 + (lam & 15);
  int j = n >> 2, gate = n & 3, row = gate * 50 + j;  // PyTorch gate order i,f,g,o
  _Float16 o8[8];
#pragma unroll
  for (int jj = 0; jj < 8; ++jj) {
    int k = s * 32 + (lam >> 4) * 8 + jj;
    float v = 0.f;
    if (j < H) {
      if (s < 2) {                       // x-part, k in [0,64)
        int ksz = (l == 0) ? IN : H;
        if (k < ksz) v = (l == 0) ? w_ih0[row * IN + k]
                                  : w_ihL[((size_t)(l - 1) * 200 + row) * H + k];
      } else {                           // h-part
        int kh = k - 64;
        if (kh < H)        v = w_hh[((size_t)l * 200 + row) * H + kh];
        else if (kh == 63) v = b_ih[l * 200 + row] + b_hh[l * 200 + row];  // bias
      }
    }
    o8[jj] = (_Float16)v;
  }
  ((half8*)wbuf)[t] = *(half8*)o8;
}

// ---------------- main kernel ----------------
__global__ __launch_bounds__(BLK, 4)   // cap 128 VGPR; ~80 expected -> 4 waves/SIMD
void lstm_mfma(const float* __restrict__ x,   const float* __restrict__ h0,
               const float* __restrict__ c0,  const float* __restrict__ fc_w,
               const float* __restrict__ fc_b, const _Float16* __restrict__ wbuf,
               float* __restrict__ out, int B) {
  const int tid = threadIdx.x;
  const int lam = tid & 63;
  const int q   = lam >> 4;
  const int lm  = lam & 15;
  const int bbase = blockIdx.x * M;
  const int ng  = __builtin_amdgcn_readfirstlane(tid >> 6);
  const int ntp = __builtin_amdgcn_readfirstlane((ng + blockIdx.x) & 7);  // pad-tile spread

  __shared__ __align__(16) _Float16 ys[2][T][M][ROWS];

  // ---- stage x into ys[0]; init ys[1] pad (k>=50 zero, k==63 = 1.0) ----
  for (int idx = tid; idx < T * M * 64; idx += BLK) {
    int t = idx >> 11, m = (idx >> 6) & 31, k = idx & 63;
    float v = (k < IN) ? x[(size_t)(bbase + m) * (IN * T) + k * T + t]
                       : (k == 63 ? 1.f : 0.f);
    ys[0][t][m][k] = (_Float16)v;
    ys[1][t][m][k] = (_Float16)((k == 63) ? 1.f : 0.f);
  }

  float c[2][2];
  f32x4 acc[2][2];
  half8 W[2][4];   // [nt][kslab] — 32 VGPRs

  for (int l = 0; l < L; ++l) {
    const int sb = l & 1, db = sb ^ 1;
    // ---- c0 straight to registers (lane-local; block-aggregate is contiguous)
#pragma unroll
    for (int nt = 0; nt < 2; ++nt)
#pragma unroll
      for (int mt = 0; mt < 2; ++mt) {
        int j = 4 * (2 * ntp + nt) + q, m = mt * 16 + lm;
        c[nt][mt] = (j < H) ? c0[((size_t)l * B + bbase + m) * H + j] : 0.f;
      }
    // ---- W fragments for this layer (coalesced dwordx4, L2-hot) ----
#pragma unroll
    for (int nt = 0; nt < 2; ++nt)
#pragma unroll
      for (int s = 0; s < 4; ++s)
        W[nt][s] = ((const half8*)wbuf)[((l * 4 + s) * 16 + (2 * ntp + nt)) * 64 + lam];
    // ---- stage h0 into ys[db][T-1] (slot dead until step T-1 writes it) ----
    for (int idx = tid; idx < M * 64; idx += BLK) {
      int m = idx >> 6, k = idx & 63;
      float v = (k < H) ? h0[((size_t)l * B + bbase + m) * H + k]
                        : (k == 63 ? 1.f : 0.f);
      ys[db][T - 1][m][k] = (_Float16)v;
    }
    __syncthreads();

#pragma unroll
    for (int t = 0; t < T; ++t) {
      const int hs = (t == 0) ? T - 1 : t - 1;   // h-source slot in dst buffer
#pragma unroll
      for (int nt = 0; nt < 2; ++nt)
#pragma unroll
        for (int mt = 0; mt < 2; ++mt) acc[nt][mt] = (f32x4){0.f, 0.f, 0.f, 0.f};

#pragma unroll
      for (int s = 0; s < 4; ++s) {
        const _Float16* base = (s < 2) ? &ys[sb][t][0][0] : &ys[db][hs][0][0];
        const int koff = (s & 1) * 32;
        half8 Xf[2];
#pragma unroll
        for (int mt = 0; mt < 2; ++mt)   // B-frag: col m = lane&15, k = q*8+jj
          Xf[mt] = *(const half8*)(base + (mt * 16 + lm) * ROWS + koff + q * 8);
#pragma unroll
        for (int nt = 0; nt < 2; ++nt)
#pragma unroll
          for (int mt = 0; mt < 2; ++mt)
            acc[nt][mt] = __builtin_amdgcn_mfma_f32_16x16x32_f16(W[nt][s], Xf[mt], acc[nt][mt], 0, 0, 0);
      }

      // ---- h-phase: acc regs 0..3 = gates i,f,g,o of unit j (lane-local) ----
#pragma unroll
      for (int nt = 0; nt < 2; ++nt)
#pragma unroll
        for (int mt = 0; mt < 2; ++mt) {
          float ig = sigm(acc[nt][mt][0]);
          float fg = sigm(acc[nt][mt][1]);
          float gg = tanh_(acc[nt][mt][2]);
          float og = sigm(acc[nt][mt][3]);
          float cv = fg * c[nt][mt] + ig * gg;
          c[nt][mt] = cv;
          float hv = og * tanh_(cv);
          int j = 4 * (2 * ntp + nt) + q;
          if (j < H) {                    // keep pad cols (and k63=1.0) intact
            int m = mt * 16 + lm;
            ys[db][t][m][j] = (_Float16)hv;
          }
        }
      __syncthreads();   // h_t (and, at t=T-1, layer output) visible
    }
  }

  // ---- fc tail: out[b] = fc_w · h_last + fc_b ; final dst buffer = ys[0] ----
  {
    int m = tid >> 4, strip = tid & 15;
    float part = 0.f;
#pragma unroll
    for (int jj = 0; jj < 4; ++jj) {
      int j = strip * 4 + jj;
      if (j < H) part += fc_w[j] * (float)ys[0][T - 1][m][j];
    }
    part += __shfl_xor(part, 8);
    part += __shfl_xor(part, 4);
    part += __shfl_xor(part, 2);
    part += __shfl_xor(part, 1);
    if (strip == 0) out[bbase + m] = part + fc_b[0];
  }
}

}  // namespace

extern "C" void kernel_launch(void* const* d_in, const int* in_sizes, int n_in,
                              void* d_out, int out_size, void* d_ws, size_t ws_size,
                              hipStream_t stream) {
  const float* x     = (const float*)d_in[0];
  const float* h0    = (const float*)d_in[1];
  const float* c0    = (const float*)d_in[2];
  const float* w_ih0 = (const float*)d_in[3];
  const float* w_ih  = (const float*)d_in[4];
  const float* w_hh  = (const float*)d_in[5];
  const float* b_ih  = (const float*)d_in[6];
  const float* b_hh  = (const float*)d_in[7];
  const float* fc_w  = (const float*)d_in[8];
  const float* fc_b  = (const float*)d_in[9];
  float* out         = (float*)d_out;

  const int B = in_sizes[0] / (IN * T);  // 65536
  _Float16* wbuf = (_Float16*)d_ws;      // 384 frags * 64 lanes * 16 B = 393 KB

  wprep<<<(384 * 64 + 255) / 256, 256, 0, stream>>>(w_ih0, w_ih, w_hh, b_ih, b_hh, wbuf);
  lstm_mfma<<<B / M, BLK, 0, stream>>>(x, h0, c0, fc_w, fc_b, wbuf, out, B);
}

// Round 7
// 314.773 us; speedup vs baseline: 14.1545x; 1.0600x over previous
//
#include <hip/hip_runtime.h>

// LSTM B=65536, L=6, H=50, T=3, IN=3, FC 50->1 — fp16 MFMA, R7.
//
// R7 vs R6 (209us kernel, ~110us stall): amortize the per-step barrier and
// drop pad-tile work.
//  - M=64 samples/block (4 m-tiles of 16). 2x issue work per barrier interval
//    amortizes the lockstep stall (still 2 blocks/CU: LDS 55.3KB).
//  - Live-mask: n-tiles ntg>=13 are pure padding (j>=52). Wave-uniform skip of
//    their W loads, c0, MFMA, activations, stores (13/16 tiles live -> -19%
//    MFMA and -19% transcendental VALU). Pad cols stay zero by init invariant.
//  - Same numerics as R6: single-term fp16 (z-noise ~2.4e-4), ping-pong ys,
//    h0 staged into dst[T-1], bias folded at h-part k=63 vs const-1.0 column,
//    one barrier per step.
// Layout: gates^T = W·X^T, n = 4j+gate; C row = 4q+reg -> lane holds all 4
// gates of unit j = 4*ntg+q (lane-local c/h update).

namespace {

constexpr int H  = 50;
constexpr int L  = 6;
constexpr int T  = 3;
constexpr int IN = 3;
constexpr int M  = 64;     // samples per block (4 m-tiles)
constexpr int BLK = 512;   // 8 waves
constexpr int ROWS = 72;   // _Float16 row stride (144 B)

using half8 = __attribute__((ext_vector_type(8))) _Float16;
using f32x4 = __attribute__((ext_vector_type(4))) float;

__device__ __forceinline__ float fexp(float x) { return __builtin_amdgcn_exp2f(x * 1.44269504088896f); }
__device__ __forceinline__ float sigm(float x) { return __builtin_amdgcn_rcpf(1.f + fexp(-x)); }
__device__ __forceinline__ float tanh_(float x) { return 1.f - 2.f * __builtin_amdgcn_rcpf(1.f + fexp(2.f * x)); }

// ---------------- prologue: pack fp16 A-fragments ----------------
// frag id f = (l*4 + s)*16 + nt ; lane's frag: W[n=16*nt+(lam&15)][k=32*s+(lam>>4)*8+jj]
__global__ void wprep(const float* __restrict__ w_ih0, const float* __restrict__ w_ihL,
                      const float* __restrict__ w_hh,  const float* __restrict__ b_ih,
                      const float* __restrict__ b_hh,  _Float16* __restrict__ wbuf) {
  int t = blockIdx.x * 256 + threadIdx.x;
  if (t >= 384 * 64) return;
  int lam = t & 63, f = t >> 6;
  int nt = f & 15, s = (f >> 4) & 3, l = f >> 6;
  int n = nt * 16 + (lam & 15);
  int j = n >> 2, gate = n & 3, row = gate * 50 + j;  // PyTorch gate order i,f,g,o
  _Float16 o8[8];
#pragma unroll
  for (int jj = 0; jj < 8; ++jj) {
    int k = s * 32 + (lam >> 4) * 8 + jj;
    float v = 0.f;
    if (j < H) {
      if (s < 2) {                       // x-part, k in [0,64)
        int ksz = (l == 0) ? IN : H;
        if (k < ksz) v = (l == 0) ? w_ih0[row * IN + k]
                                  : w_ihL[((size_t)(l - 1) * 200 + row) * H + k];
      } else {                           // h-part
        int kh = k - 64;
        if (kh < H)        v = w_hh[((size_t)l * 200 + row) * H + kh];
        else if (kh == 63) v = b_ih[l * 200 + row] + b_hh[l * 200 + row];  // bias
      }
    }
    o8[jj] = (_Float16)v;
  }
  ((half8*)wbuf)[t] = *(half8*)o8;
}

// ---------------- main kernel ----------------
__global__ __launch_bounds__(BLK, 4)   // cap 128 regs; est ~80 VGPR + 32 AGPR
void lstm_mfma(const float* __restrict__ x,   const float* __restrict__ h0,
               const float* __restrict__ c0,  const float* __restrict__ fc_w,
               const float* __restrict__ fc_b, const _Float16* __restrict__ wbuf,
               float* __restrict__ out, int B) {
  const int tid = threadIdx.x;
  const int lam = tid & 63;
  const int q   = lam >> 4;
  const int lm  = lam & 15;
  const int bbase = blockIdx.x * M;
  const int ng  = __builtin_amdgcn_readfirstlane(tid >> 6);
  const int ntp = __builtin_amdgcn_readfirstlane((ng + blockIdx.x) & 7);  // pad-wave rotation
  const int ntg0 = 2 * ntp, ntg1 = 2 * ntp + 1;
  const bool live0 = (ntg0 <= 12);          // tiles 13..15 are pure padding (j>=52)
  const bool live1 = (ntg1 <= 12);

  __shared__ __align__(16) _Float16 ys[2][T][M][ROWS];

  // ---- stage x into ys[0]; init ys[1] pad (k>=50 zero, k==63 = 1.0) ----
  for (int idx = tid; idx < T * M * 64; idx += BLK) {
    int t = idx >> 12, m = (idx >> 6) & 63, k = idx & 63;
    float v = (k < IN) ? x[(size_t)(bbase + m) * (IN * T) + k * T + t]
                       : (k == 63 ? 1.f : 0.f);
    ys[0][t][m][k] = (_Float16)v;
    ys[1][t][m][k] = (_Float16)((k == 63) ? 1.f : 0.f);
  }

  float c[2][4];
  f32x4 acc[2][4];
  half8 W[2][4];   // [nt][kslab] — 32 regs

  for (int l = 0; l < L; ++l) {
    const int sb = l & 1, db = sb ^ 1;
    // ---- c0 straight to registers (dead tiles skipped) ----
#pragma unroll
    for (int nt = 0; nt < 2; ++nt) {
      const int ntg = nt ? ntg1 : ntg0;
      const bool lv = nt ? live1 : live0;
      const int j = 4 * ntg + q;
#pragma unroll
      for (int mt = 0; mt < 4; ++mt)
        c[nt][mt] = (lv && j < H)
            ? c0[((size_t)l * B + bbase + mt * 16 + lm) * H + j] : 0.f;
    }
    // ---- W fragments for this layer (live tiles only, coalesced dwordx4) ----
#pragma unroll
    for (int nt = 0; nt < 2; ++nt) {
      const int ntg = nt ? ntg1 : ntg0;
      const bool lv = nt ? live1 : live0;
      if (lv)
#pragma unroll
        for (int s = 0; s < 4; ++s)
          W[nt][s] = ((const half8*)wbuf)[((l * 4 + s) * 16 + ntg) * 64 + lam];
    }
    // ---- stage h0 into ys[db][T-1] (slot dead until step T-1 writes it) ----
    for (int idx = tid; idx < M * 64; idx += BLK) {
      int m = idx >> 6, k = idx & 63;
      float v = (k < H) ? h0[((size_t)l * B + bbase + m) * H + k]
                        : (k == 63 ? 1.f : 0.f);
      ys[db][T - 1][m][k] = (_Float16)v;
    }
    __syncthreads();

#pragma unroll
    for (int t = 0; t < T; ++t) {
      const int hs = (t == 0) ? T - 1 : t - 1;   // h-source slot in dst buffer
#pragma unroll
      for (int nt = 0; nt < 2; ++nt)
#pragma unroll
        for (int mt = 0; mt < 4; ++mt) acc[nt][mt] = (f32x4){0.f, 0.f, 0.f, 0.f};

      if (live0) {   // wave with both tiles dead skips all compute
#pragma unroll
        for (int s = 0; s < 4; ++s) {
          const _Float16* base = (s < 2) ? &ys[sb][t][0][0] : &ys[db][hs][0][0];
          const int koff = (s & 1) * 32;
          half8 Xf[4];
#pragma unroll
          for (int mt = 0; mt < 4; ++mt)  // B-frag: col m = lane&15, k = q*8+jj
            Xf[mt] = *(const half8*)(base + (mt * 16 + lm) * ROWS + koff + q * 8);
#pragma unroll
          for (int mt = 0; mt < 4; ++mt)
            acc[0][mt] = __builtin_amdgcn_mfma_f32_16x16x32_f16(W[0][s], Xf[mt], acc[0][mt], 0, 0, 0);
          if (live1)
#pragma unroll
            for (int mt = 0; mt < 4; ++mt)
              acc[1][mt] = __builtin_amdgcn_mfma_f32_16x16x32_f16(W[1][s], Xf[mt], acc[1][mt], 0, 0, 0);
        }

        // ---- h-phase: acc regs 0..3 = gates i,f,g,o of unit j (lane-local) --
#pragma unroll
        for (int nt = 0; nt < 2; ++nt) {
          const int ntg = nt ? ntg1 : ntg0;
          const bool lv = nt ? live1 : live0;
          if (!lv) continue;
          const int j = 4 * ntg + q;
#pragma unroll
          for (int mt = 0; mt < 4; ++mt) {
            float ig = sigm(acc[nt][mt][0]);
            float fg = sigm(acc[nt][mt][1]);
            float gg = tanh_(acc[nt][mt][2]);
            float og = sigm(acc[nt][mt][3]);
            float cv = fg * c[nt][mt] + ig * gg;
            c[nt][mt] = cv;
            float hv = og * tanh_(cv);
            if (j < H)                    // keep pad cols (and k63=1.0) intact
              ys[db][t][mt * 16 + lm][j] = (_Float16)hv;
          }
        }
      }
      __syncthreads();   // h_t (and, at t=T-1, layer output) visible
    }
  }

  // ---- fc tail: out[b] = fc_w · h_last + fc_b ; final dst buffer = ys[0] ----
  {
    int m = tid >> 3, strip = tid & 7;
    float part = 0.f;
#pragma unroll
    for (int jj = 0; jj < 7; ++jj) {
      int j = strip + 8 * jj;
      if (j < H) part += fc_w[j] * (float)ys[0][T - 1][m][j];
    }
    part += __shfl_xor(part, 4);
    part += __shfl_xor(part, 2);
    part += __shfl_xor(part, 1);
    if (strip == 0) out[bbase + m] = part + fc_b[0];
  }
}

}  // namespace

extern "C" void kernel_launch(void* const* d_in, const int* in_sizes, int n_in,
                              void* d_out, int out_size, void* d_ws, size_t ws_size,
                              hipStream_t stream) {
  const float* x     = (const float*)d_in[0];
  const float* h0    = (const float*)d_in[1];
  const float* c0    = (const float*)d_in[2];
  const float* w_ih0 = (const float*)d_in[3];
  const float* w_ih  = (const float*)d_in[4];
  const float* w_hh  = (const float*)d_in[5];
  const float* b_ih  = (const float*)d_in[6];
  const float* b_hh  = (const float*)d_in[7];
  const float* fc_w  = (const float*)d_in[8];
  const float* fc_b  = (const float*)d_in[9];
  float* out         = (float*)d_out;

  const int B = in_sizes[0] / (IN * T);  // 65536
  _Float16* wbuf = (_Float16*)d_ws;      // 384 frags * 64 lanes * 16 B = 393 KB

  wprep<<<(384 * 64 + 255) / 256, 256, 0, stream>>>(w_ih0, w_ih, w_hh, b_ih, b_hh, wbuf);
  lstm_mfma<<<B / M, BLK, 0, stream>>>(x, h0, c0, fc_w, fc_b, wbuf, out, B);
}